// Round 5
// baseline (1033.436 us; speedup 1.0000x reference)
//
#include <hip/hip_runtime.h>
#include <hip/hip_bf16.h>

#define N_USERS 100000
#define N_ITEMS 50000
#define N_NODES 150000
#define N_REL 5
#define NNZ 2000000
#define D 64
#define B_EVAL 16384
#define MAXSLOTS 32768
#define NBINS (MAXSLOTS * N_REL)      /* 163840 = 160 * 1024 */
#define TOTAL_EDGES (N_REL * NNZ)     /* 10,000,000 */
#define RECCAP 2400000                /* passing edges ~1.94M deterministic */

typedef __hip_bfloat16 bf16;

// -------- workspace layout (bytes), total 50,472,576 <= proven 50.9 MB ----
// map:    int[150000]        @ 0
// cnt:    int                @ 600,064
// bincnt: int[163840]        @ 600,320
// offs:   int[163840]        @ 1,255,680
// bsum:   int[160]           @ 1,911,040
// bexcl:  int[160]           @ 1,911,808
// recs:   uint2[2,400,000]   @ 1,912,448   (19.2 MB)
// agg:    bf16[32768*320]    @ 21,112,448  (21.0 MB)
// logits: float[32768*64]    @ 42,083,968  ( 8.4 MB)
#define OFF_MAP   0
#define OFF_CNT   600064
#define OFF_BCNT  600320
#define OFF_OFFS  1255680
#define OFF_BSUM  1911040
#define OFF_BEXCL 1911808
#define OFF_RECS  1912448
#define OFF_AGG   21112448
#define OFF_LOG   42083968

__global__ __launch_bounds__(256) void build_map(const int* __restrict__ users,
                                                 const int* __restrict__ items,
                                                 int* __restrict__ map,
                                                 int* __restrict__ cnt) {
    int t = blockIdx.x * 256 + threadIdx.x;
    if (t >= 2 * B_EVAL) return;
    int node = (t < B_EVAL) ? users[t] : (N_USERS + items[t - B_EVAL]);
    if (atomicCAS(&map[node], -1, -2) == -1) {
        int idx = atomicAdd(cnt, 1);
        map[node] = idx;
    }
}

__global__ __launch_bounds__(256) void count_edges(const int* __restrict__ rows,
                                                   const int* __restrict__ map,
                                                   int* __restrict__ bincnt) {
    int gid = blockIdx.x * 256 + threadIdx.x;
    if (gid >= TOTAL_EDGES) return;
    int ci = map[rows[gid]];
    if (ci >= 0) atomicAdd(&bincnt[ci * N_REL + gid / NNZ], 1);
}

// exclusive scan over NBINS = 160 blocks x 1024
__global__ __launch_bounds__(1024) void scan_blocks(const int* __restrict__ cnts,
                                                    int* __restrict__ offs,
                                                    int* __restrict__ bsum) {
    __shared__ int sh[1024];
    int t = threadIdx.x;
    int g = blockIdx.x * 1024 + t;
    int v = cnts[g];
    sh[t] = v;
    __syncthreads();
    int acc = v;
    for (int off = 1; off < 1024; off <<= 1) {
        int add = (t >= off) ? sh[t - off] : 0;
        __syncthreads();
        acc += add;
        sh[t] = acc;
        __syncthreads();
    }
    offs[g] = acc - v;                      // block-local exclusive
    if (t == 1023) bsum[blockIdx.x] = acc;  // block total
}

__global__ __launch_bounds__(256) void scan_tops(const int* __restrict__ bsum,
                                                 int* __restrict__ bexcl) {
    __shared__ int sh[256];
    int t = threadIdx.x;
    int v = (t < NBINS / 1024) ? bsum[t] : 0;
    sh[t] = v;
    __syncthreads();
    int acc = v;
    for (int off = 1; off < 256; off <<= 1) {
        int add = (t >= off) ? sh[t - off] : 0;
        __syncthreads();
        acc += add;
        sh[t] = acc;
        __syncthreads();
    }
    if (t < NBINS / 1024) bexcl[t] = acc - v;
}

__global__ __launch_bounds__(1024) void scan_add(int* __restrict__ offs,
                                                 const int* __restrict__ bexcl) {
    int g = blockIdx.x * 1024 + threadIdx.x;
    offs[g] += bexcl[blockIdx.x];
}

__global__ __launch_bounds__(256) void fill_records(const int* __restrict__ rows,
                                                    const int* __restrict__ cols,
                                                    const float* __restrict__ vals,
                                                    const int* __restrict__ map,
                                                    int* __restrict__ offs,
                                                    uint2* __restrict__ recs) {
    int gid = blockIdx.x * 256 + threadIdx.x;
    if (gid >= TOTAL_EDGES) return;
    int ci = map[rows[gid]];
    if (ci < 0) return;
    int bin = ci * N_REL + gid / NNZ;
    int pos = atomicAdd(&offs[bin], 1);     // offs becomes end-of-bin after this pass
    if (pos < RECCAP)
        recs[pos] = make_uint2((unsigned)cols[gid], __float_as_uint(vals[gid]));
}

// one wave per (slot, rel) bin: gather-accumulate in registers, store once.
__global__ __launch_bounds__(256) void gather_bins(const uint2* __restrict__ recs,
                                                   const float* __restrict__ uemb,
                                                   const float* __restrict__ iemb,
                                                   const int* __restrict__ offs,
                                                   const int* __restrict__ bincnt,
                                                   const int* __restrict__ cnt,
                                                   bf16* __restrict__ agg) {
    int wid = (blockIdx.x * 256 + threadIdx.x) >> 6;
    int lane = threadIdx.x & 63;
    if (wid >= NBINS) return;
    int slot = wid / N_REL;
    if (slot >= *cnt) return;
    int end = offs[wid];              // post-fill = start + count
    int n = bincnt[wid];
    int start = end - n;

    float acc = 0.0f;
    uint2 nrec = (start < end) ? recs[start] : make_uint2(0, 0);
    for (int e = start; e < end; e++) {
        uint2 rec = nrec;
        if (e + 1 < end) nrec = recs[e + 1];   // prefetch next record
        int col = (int)rec.x;
        float v = __uint_as_float(rec.y);
        const float* erow = (col < N_USERS) ? (uemb + (size_t)col * D)
                                            : (iemb + (size_t)(col - N_USERS) * D);
        acc = fmaf(erow[lane], v, acc);
    }
    agg[(size_t)wid * D + lane] = __float2bfloat16(acc);   // 128B coalesced per wave
}

// Block = 320 threads = 5 waves; wave w owns relation w AND affine chunk w.
__global__ __launch_bounds__(320) void dense_fused(const bf16* __restrict__ agg,
                                                   const float* __restrict__ Wrel,
                                                   const float* __restrict__ brel,
                                                   const float* __restrict__ affW,
                                                   const float* __restrict__ affb,
                                                   const int* __restrict__ cnt,
                                                   float* __restrict__ logits) {
    int lane = threadIdx.x & 63;
    int w    = threadIdx.x >> 6;   // 0..4
    int cval = *cnt;

    float Wr[64], Wa[64];
    #pragma unroll
    for (int d = 0; d < 64; d++) Wr[d] = Wrel[(size_t)(w * 64 + d) * 64 + lane];
    #pragma unroll
    for (int d = 0; d < 64; d++) Wa[d] = affW[(size_t)(w * 64 + d) * 64 + lane];
    float bw = brel[w * 64 + lane];
    float ab = affb[lane];

    __shared__ float part[5][64];

    for (int s = blockIdx.x; s < cval; s += gridDim.x) {
        float a = __bfloat162float(agg[(size_t)s * 320 + w * 64 + lane]);
        float acc = bw;
        #pragma unroll
        for (int d = 0; d < 64; d++) acc += __shfl(a, d) * Wr[d];
        acc = (acc > 0.0f) ? acc : 0.2f * acc;       // leaky_relu 0.2
        float p = 0.0f;
        #pragma unroll
        for (int d = 0; d < 64; d++) p += __shfl(acc, d) * Wa[d];
        part[w][lane] = p;
        __syncthreads();
        if (w == 0) {
            logits[(size_t)s * 64 + lane] = ab + part[0][lane] + part[1][lane]
                                          + part[2][lane] + part[3][lane] + part[4][lane];
        }
        __syncthreads();
    }
}

__global__ __launch_bounds__(256) void finalize(const int* __restrict__ users,
                                                const int* __restrict__ items,
                                                const int* __restrict__ map,
                                                const float* __restrict__ logits,
                                                float* __restrict__ out) {
    int wave = (blockIdx.x * 256 + threadIdx.x) >> 6;
    int lane = threadIdx.x & 63;
    if (wave >= B_EVAL) return;
    int cu = map[users[wave]];
    int ci = map[N_USERS + items[wave]];
    float p = logits[(size_t)cu * D + lane] * logits[(size_t)ci * D + lane];
    #pragma unroll
    for (int off = 32; off > 0; off >>= 1) p += __shfl_down(p, off);
    if (lane == 0) out[wave] = p;
}

extern "C" void kernel_launch(void* const* d_in, const int* in_sizes, int n_in,
                              void* d_out, int out_size, void* d_ws, size_t ws_size,
                              hipStream_t stream) {
    const int*   users = (const int*)d_in[0];
    const int*   items = (const int*)d_in[1];
    const int*   rows  = (const int*)d_in[2];
    const int*   cols  = (const int*)d_in[3];
    const float* vals  = (const float*)d_in[4];
    const float* uemb  = (const float*)d_in[5];
    const float* iemb  = (const float*)d_in[6];
    const float* Wrel  = (const float*)d_in[7];
    const float* brel  = (const float*)d_in[8];
    const float* affW  = (const float*)d_in[9];
    const float* affb  = (const float*)d_in[10];
    float* out = (float*)d_out;

    char* ws = (char*)d_ws;
    int*   map    = (int*)(ws + OFF_MAP);
    int*   cnt    = (int*)(ws + OFF_CNT);
    int*   bincnt = (int*)(ws + OFF_BCNT);
    int*   offs   = (int*)(ws + OFF_OFFS);
    int*   bsum   = (int*)(ws + OFF_BSUM);
    int*   bexcl  = (int*)(ws + OFF_BEXCL);
    uint2* recs   = (uint2*)(ws + OFF_RECS);
    bf16*  agg    = (bf16*)(ws + OFF_AGG);
    float* logits = (float*)(ws + OFF_LOG);

    // workspace re-poisoned before every call: re-init every time
    (void)hipMemsetAsync(map, 0xFF, (size_t)N_NODES * sizeof(int), stream);  // map = -1
    (void)hipMemsetAsync(cnt, 0, sizeof(int), stream);
    (void)hipMemsetAsync(bincnt, 0, (size_t)NBINS * sizeof(int), stream);

    build_map<<<(2 * B_EVAL + 255) / 256, 256, 0, stream>>>(users, items, map, cnt);
    count_edges<<<(TOTAL_EDGES + 255) / 256, 256, 0, stream>>>(rows, map, bincnt);
    scan_blocks<<<NBINS / 1024, 1024, 0, stream>>>(bincnt, offs, bsum);
    scan_tops<<<1, 256, 0, stream>>>(bsum, bexcl);
    scan_add<<<NBINS / 1024, 1024, 0, stream>>>(offs, bexcl);
    fill_records<<<(TOTAL_EDGES + 255) / 256, 256, 0, stream>>>(rows, cols, vals, map, offs, recs);
    gather_bins<<<(NBINS * 64) / 256, 256, 0, stream>>>(recs, uemb, iemb, offs, bincnt, cnt, agg);
    dense_fused<<<1024, 320, 0, stream>>>(agg, Wrel, brel, affW, affb, cnt, logits);
    finalize<<<(B_EVAL * 64) / 256, 256, 0, stream>>>(users, items, map, logits, out);
}

// Round 6
// 578.144 us; speedup vs baseline: 1.7875x; 1.7875x over previous
//
#include <hip/hip_runtime.h>

#define N_USERS 100000
#define N_ITEMS 50000
#define N_NODES 150000
#define N_REL 5
#define NNZ 2000000
#define D 64
#define B_EVAL 16384
#define MAXSLOTS 32768
#define NBINS (MAXSLOTS * N_REL)      /* 163840 = 160 * 1024 */
#define TOTAL_EDGES (N_REL * NNZ)     /* 10,000,000 */
#define RECCAP 2400000                /* passing edges ~1.94M (deterministic) */

// -------- workspace layout (bytes) ----
// map:    int[150000]        @ 0
// cnt:    int                @ 600,064
// bincnt: int[163840]        @ 600,320
// offs:   int[163840]        @ 1,255,680
// bsum:   int[160]           @ 1,911,040
// bexcl:  int[160]           @ 1,911,808
// recs:   uint2[2,400,000]   @ 1,912,448   (19.2 MB)
// agg:    bf16[32768*320]    @ 21,112,448  (21.0 MB)
// logits: float[32768*64]    @ 42,083,968  ( 8.4 MB)
#define OFF_MAP   0
#define OFF_CNT   600064
#define OFF_BCNT  600320
#define OFF_OFFS  1255680
#define OFF_BSUM  1911040
#define OFF_BEXCL 1911808
#define OFF_RECS  1912448
#define OFF_AGG   21112448
#define OFF_LOG   42083968

__device__ __forceinline__ unsigned short f2bf(float f) {   // RNE f32->bf16
    unsigned u = __float_as_uint(f);
    return (unsigned short)((u + 0x7FFFu + ((u >> 16) & 1u)) >> 16);
}
__device__ __forceinline__ float bflo(unsigned p) { return __uint_as_float(p << 16); }
__device__ __forceinline__ float bfhi(unsigned p) { return __uint_as_float(p & 0xFFFF0000u); }

__global__ __launch_bounds__(256) void build_map(const int* __restrict__ users,
                                                 const int* __restrict__ items,
                                                 int* __restrict__ map,
                                                 int* __restrict__ cnt) {
    int t = blockIdx.x * 256 + threadIdx.x;
    if (t >= 2 * B_EVAL) return;
    int node = (t < B_EVAL) ? users[t] : (N_USERS + items[t - B_EVAL]);
    if (atomicCAS(&map[node], -1, -2) == -1) {
        int idx = atomicAdd(cnt, 1);
        map[node] = idx;
    }
}

__global__ __launch_bounds__(256) void count_edges(const int* __restrict__ rows,
                                                   const int* __restrict__ map,
                                                   int* __restrict__ bincnt) {
    int gid = blockIdx.x * 256 + threadIdx.x;
    if (gid >= TOTAL_EDGES) return;
    int ci = map[rows[gid]];
    if (ci >= 0) atomicAdd(&bincnt[ci * N_REL + gid / NNZ], 1);
}

__global__ __launch_bounds__(1024) void scan_blocks(const int* __restrict__ cnts,
                                                    int* __restrict__ offs,
                                                    int* __restrict__ bsum) {
    __shared__ int sh[1024];
    int t = threadIdx.x;
    int g = blockIdx.x * 1024 + t;
    int v = cnts[g];
    sh[t] = v;
    __syncthreads();
    int acc = v;
    for (int off = 1; off < 1024; off <<= 1) {
        int add = (t >= off) ? sh[t - off] : 0;
        __syncthreads();
        acc += add;
        sh[t] = acc;
        __syncthreads();
    }
    offs[g] = acc - v;
    if (t == 1023) bsum[blockIdx.x] = acc;
}

__global__ __launch_bounds__(256) void scan_tops(const int* __restrict__ bsum,
                                                 int* __restrict__ bexcl) {
    __shared__ int sh[256];
    int t = threadIdx.x;
    int v = (t < NBINS / 1024) ? bsum[t] : 0;
    sh[t] = v;
    __syncthreads();
    int acc = v;
    for (int off = 1; off < 256; off <<= 1) {
        int add = (t >= off) ? sh[t - off] : 0;
        __syncthreads();
        acc += add;
        sh[t] = acc;
        __syncthreads();
    }
    if (t < NBINS / 1024) bexcl[t] = acc - v;
}

__global__ __launch_bounds__(1024) void scan_add(int* __restrict__ offs,
                                                 const int* __restrict__ bexcl) {
    int g = blockIdx.x * 1024 + threadIdx.x;
    offs[g] += bexcl[blockIdx.x];
}

__global__ __launch_bounds__(256) void fill_records(const int* __restrict__ rows,
                                                    const int* __restrict__ cols,
                                                    const float* __restrict__ vals,
                                                    const int* __restrict__ map,
                                                    int* __restrict__ offs,
                                                    uint2* __restrict__ recs) {
    int gid = blockIdx.x * 256 + threadIdx.x;
    if (gid >= TOTAL_EDGES) return;
    int ci = map[rows[gid]];
    if (ci < 0) return;
    int bin = ci * N_REL + gid / NNZ;
    int pos = atomicAdd(&offs[bin], 1);
    if (pos < RECCAP)
        recs[pos] = make_uint2((unsigned)cols[gid], __float_as_uint(vals[gid]));
}

// one wave per (slot, rel) bin; unroll-4 for memory-level parallelism
__global__ __launch_bounds__(256) void gather_bins(const uint2* __restrict__ recs,
                                                   const float* __restrict__ uemb,
                                                   const float* __restrict__ iemb,
                                                   const int* __restrict__ offs,
                                                   const int* __restrict__ bincnt,
                                                   const int* __restrict__ cnt,
                                                   unsigned short* __restrict__ agg) {
    int wid = (blockIdx.x * 256 + threadIdx.x) >> 6;
    int lane = threadIdx.x & 63;
    if (wid >= NBINS) return;
    if ((wid / N_REL) >= *cnt) return;
    int end = offs[wid];
    int start = end - bincnt[wid];

    float acc0 = 0.0f, acc1 = 0.0f;
    int e = start;
    for (; e + 4 <= end; e += 4) {
        uint2 r0 = recs[e], r1 = recs[e + 1], r2 = recs[e + 2], r3 = recs[e + 3];
        const float* p0 = (r0.x < N_USERS) ? uemb + (size_t)r0.x * D : iemb + (size_t)(r0.x - N_USERS) * D;
        const float* p1 = (r1.x < N_USERS) ? uemb + (size_t)r1.x * D : iemb + (size_t)(r1.x - N_USERS) * D;
        const float* p2 = (r2.x < N_USERS) ? uemb + (size_t)r2.x * D : iemb + (size_t)(r2.x - N_USERS) * D;
        const float* p3 = (r3.x < N_USERS) ? uemb + (size_t)r3.x * D : iemb + (size_t)(r3.x - N_USERS) * D;
        float e0 = p0[lane], e1 = p1[lane], e2 = p2[lane], e3 = p3[lane];
        acc0 = fmaf(e0, __uint_as_float(r0.y), acc0);
        acc1 = fmaf(e1, __uint_as_float(r1.y), acc1);
        acc0 = fmaf(e2, __uint_as_float(r2.y), acc0);
        acc1 = fmaf(e3, __uint_as_float(r3.y), acc1);
    }
    for (; e < end; e++) {
        uint2 r = recs[e];
        const float* p = (r.x < N_USERS) ? uemb + (size_t)r.x * D : iemb + (size_t)(r.x - N_USERS) * D;
        acc0 = fmaf(p[lane], __uint_as_float(r.y), acc0);
    }
    agg[(size_t)wid * D + lane] = f2bf(acc0 + acc1);
}

// LDS-tiled fused dense: 32 slots/block, 256 threads, 2x4 register tile/thread.
// LDS: shA bf16[32][328] + shM1 bf16[32][328] + shW f32[64][68] = 59,392 B.
__global__ __launch_bounds__(256) void dense_tile(const unsigned short* __restrict__ agg,
                                                  const float* __restrict__ Wrel,
                                                  const float* __restrict__ brel,
                                                  const float* __restrict__ affW,
                                                  const float* __restrict__ affb,
                                                  const int* __restrict__ cnt,
                                                  float* __restrict__ logits) {
    __shared__ __align__(16) unsigned short shA[32][328];
    __shared__ __align__(16) unsigned short shM1[32][328];
    __shared__ __align__(16) float shW[64][68];

    int tid = threadIdx.x;
    int ty = tid >> 4, tx = tid & 15;   // ty 0..15, tx 0..15
    int s0 = ty * 2;                    // 2 slots per thread
    int j0 = tx * 4;                    // 4 cols per thread
    int cval = *cnt;

    for (int tile = blockIdx.x; tile * 32 < cval; tile += gridDim.x) {
        __syncthreads();   // protect shA/shM1 reuse across tiles
        // ---- load A tile: 32 rows x 320 bf16, contiguous 20 KB ----
        {
            const uint4* src = (const uint4*)(agg + (size_t)tile * 32 * 320);
            #pragma unroll
            for (int i = 0; i < 5; i++) {
                int idx = tid + i * 256;            // uint4 = 8 bf16
                int p = idx * 8;
                int row = p / 320, col = p % 320;
                *(uint4*)&shA[row][col] = src[idx];
            }
        }
        // ---- stage 1: per-relation 64x64 transform + leaky ----
        #pragma unroll
        for (int k = 0; k < N_REL; k++) {
            __syncthreads();
            const float4* wsrc = (const float4*)(Wrel + (size_t)k * 4096);
            #pragma unroll
            for (int i = 0; i < 4; i++) {
                int idx = tid + i * 256;
                *(float4*)&shW[idx >> 4][(idx & 15) * 4] = wsrc[idx];
            }
            __syncthreads();
            float acc[2][4];
            #pragma unroll
            for (int jj = 0; jj < 4; jj++) {
                float b = brel[k * 64 + j0 + jj];
                acc[0][jj] = b; acc[1][jj] = b;
            }
            for (int d = 0; d < 64; d += 2) {
                unsigned pa0 = *(const unsigned*)&shA[s0][k * 64 + d];
                unsigned pa1 = *(const unsigned*)&shA[s0 + 1][k * 64 + d];
                float4 w0 = *(const float4*)&shW[d][j0];
                float4 w1 = *(const float4*)&shW[d + 1][j0];
                float a00 = bflo(pa0), a01 = bfhi(pa0);
                float a10 = bflo(pa1), a11 = bfhi(pa1);
                acc[0][0] = fmaf(a00, w0.x, fmaf(a01, w1.x, acc[0][0]));
                acc[0][1] = fmaf(a00, w0.y, fmaf(a01, w1.y, acc[0][1]));
                acc[0][2] = fmaf(a00, w0.z, fmaf(a01, w1.z, acc[0][2]));
                acc[0][3] = fmaf(a00, w0.w, fmaf(a01, w1.w, acc[0][3]));
                acc[1][0] = fmaf(a10, w0.x, fmaf(a11, w1.x, acc[1][0]));
                acc[1][1] = fmaf(a10, w0.y, fmaf(a11, w1.y, acc[1][1]));
                acc[1][2] = fmaf(a10, w0.z, fmaf(a11, w1.z, acc[1][2]));
                acc[1][3] = fmaf(a10, w0.w, fmaf(a11, w1.w, acc[1][3]));
            }
            #pragma unroll
            for (int i = 0; i < 2; i++) {
                #pragma unroll
                for (int jj = 0; jj < 4; jj++) {
                    float v = acc[i][jj];
                    acc[i][jj] = (v > 0.0f) ? v : 0.2f * v;   // leaky_relu 0.2
                }
                unsigned lo = (unsigned)f2bf(acc[i][0]) | ((unsigned)f2bf(acc[i][1]) << 16);
                unsigned hi = (unsigned)f2bf(acc[i][2]) | ((unsigned)f2bf(acc[i][3]) << 16);
                *(uint2*)&shM1[s0 + i][k * 64 + j0] = make_uint2(lo, hi);
            }
        }
        // ---- stage 2: [32x320] x [320x64] affine ----
        float acc2[2][4] = {{0,0,0,0},{0,0,0,0}};
        #pragma unroll
        for (int c = 0; c < N_REL; c++) {
            __syncthreads();   // also orders shM1 writes before reads (c==0)
            const float4* wsrc = (const float4*)(affW + (size_t)c * 4096);
            #pragma unroll
            for (int i = 0; i < 4; i++) {
                int idx = tid + i * 256;
                *(float4*)&shW[idx >> 4][(idx & 15) * 4] = wsrc[idx];
            }
            __syncthreads();
            for (int dd = 0; dd < 64; dd += 2) {
                unsigned m0 = *(const unsigned*)&shM1[s0][c * 64 + dd];
                unsigned m1 = *(const unsigned*)&shM1[s0 + 1][c * 64 + dd];
                float4 w0 = *(const float4*)&shW[dd][j0];
                float4 w1 = *(const float4*)&shW[dd + 1][j0];
                float a00 = bflo(m0), a01 = bfhi(m0);
                float a10 = bflo(m1), a11 = bfhi(m1);
                acc2[0][0] = fmaf(a00, w0.x, fmaf(a01, w1.x, acc2[0][0]));
                acc2[0][1] = fmaf(a00, w0.y, fmaf(a01, w1.y, acc2[0][1]));
                acc2[0][2] = fmaf(a00, w0.z, fmaf(a01, w1.z, acc2[0][2]));
                acc2[0][3] = fmaf(a00, w0.w, fmaf(a01, w1.w, acc2[0][3]));
                acc2[1][0] = fmaf(a10, w0.x, fmaf(a11, w1.x, acc2[1][0]));
                acc2[1][1] = fmaf(a10, w0.y, fmaf(a11, w1.y, acc2[1][1]));
                acc2[1][2] = fmaf(a10, w0.z, fmaf(a11, w1.z, acc2[1][2]));
                acc2[1][3] = fmaf(a10, w0.w, fmaf(a11, w1.w, acc2[1][3]));
            }
        }
        float4 ab = *(const float4*)&affb[j0];
        #pragma unroll
        for (int i = 0; i < 2; i++) {
            float4 r;
            r.x = acc2[i][0] + ab.x; r.y = acc2[i][1] + ab.y;
            r.z = acc2[i][2] + ab.z; r.w = acc2[i][3] + ab.w;
            *(float4*)&logits[(size_t)(tile * 32 + s0 + i) * 64 + j0] = r;
        }
    }
}

__global__ __launch_bounds__(256) void finalize(const int* __restrict__ users,
                                                const int* __restrict__ items,
                                                const int* __restrict__ map,
                                                const float* __restrict__ logits,
                                                float* __restrict__ out) {
    int wave = (blockIdx.x * 256 + threadIdx.x) >> 6;
    int lane = threadIdx.x & 63;
    if (wave >= B_EVAL) return;
    int cu = map[users[wave]];
    int ci = map[N_USERS + items[wave]];
    float p = logits[(size_t)cu * D + lane] * logits[(size_t)ci * D + lane];
    #pragma unroll
    for (int off = 32; off > 0; off >>= 1) p += __shfl_down(p, off);
    if (lane == 0) out[wave] = p;
}

extern "C" void kernel_launch(void* const* d_in, const int* in_sizes, int n_in,
                              void* d_out, int out_size, void* d_ws, size_t ws_size,
                              hipStream_t stream) {
    const int*   users = (const int*)d_in[0];
    const int*   items = (const int*)d_in[1];
    const int*   rows  = (const int*)d_in[2];
    const int*   cols  = (const int*)d_in[3];
    const float* vals  = (const float*)d_in[4];
    const float* uemb  = (const float*)d_in[5];
    const float* iemb  = (const float*)d_in[6];
    const float* Wrel  = (const float*)d_in[7];
    const float* brel  = (const float*)d_in[8];
    const float* affW  = (const float*)d_in[9];
    const float* affb  = (const float*)d_in[10];
    float* out = (float*)d_out;

    char* ws = (char*)d_ws;
    int*   map    = (int*)(ws + OFF_MAP);
    int*   cnt    = (int*)(ws + OFF_CNT);
    int*   bincnt = (int*)(ws + OFF_BCNT);
    int*   offs   = (int*)(ws + OFF_OFFS);
    int*   bsum   = (int*)(ws + OFF_BSUM);
    int*   bexcl  = (int*)(ws + OFF_BEXCL);
    uint2* recs   = (uint2*)(ws + OFF_RECS);
    unsigned short* agg = (unsigned short*)(ws + OFF_AGG);
    float* logits = (float*)(ws + OFF_LOG);

    (void)hipMemsetAsync(map, 0xFF, (size_t)N_NODES * sizeof(int), stream);  // map = -1
    (void)hipMemsetAsync(cnt, 0, sizeof(int), stream);
    (void)hipMemsetAsync(bincnt, 0, (size_t)NBINS * sizeof(int), stream);

    build_map<<<(2 * B_EVAL + 255) / 256, 256, 0, stream>>>(users, items, map, cnt);
    count_edges<<<(TOTAL_EDGES + 255) / 256, 256, 0, stream>>>(rows, map, bincnt);
    scan_blocks<<<NBINS / 1024, 1024, 0, stream>>>(bincnt, offs, bsum);
    scan_tops<<<1, 256, 0, stream>>>(bsum, bexcl);
    scan_add<<<NBINS / 1024, 1024, 0, stream>>>(offs, bexcl);
    fill_records<<<(TOTAL_EDGES + 255) / 256, 256, 0, stream>>>(rows, cols, vals, map, offs, recs);
    gather_bins<<<(NBINS * 64) / 256, 256, 0, stream>>>(recs, uemb, iemb, offs, bincnt, cnt, agg);
    dense_tile<<<1024, 256, 0, stream>>>(agg, Wrel, brel, affW, affb, cnt, logits);
    finalize<<<(B_EVAL * 64) / 256, 256, 0, stream>>>(users, items, map, logits, out);
}